// Round 7
// baseline (2778.104 us; speedup 1.0000x reference)
//
#include <hip/hip_runtime.h>

#define N_USERS 100000
#define N_ITEMS 50000
#define NTOT    150000        // N_USERS + N_ITEMS
#define E       128
#define NNZ     4800000
#define BATCH   4096
#define TILE    16            // rows per fused block
#define BSH     10            // log2(rows per bucket)
#define BROWS   1024          // rows per bucket
#define NBK     147           // ceil(NTOT / BROWS)
#define SLOT    16            // write-combine entries per bucket
#define NSEG    37            // column segments (4096 nodes = 2 MB each)
#define SEGSH   12
#define NGRP    37500         // NTOT/4 four-row groups
#define GPB     256           // groups per bucket
#define NKEY    (GPB * NSEG)  // 9472
#define SUBL    1875          // blocks per cohort sub-launch (5 x 1875 x 16 rows = 150000)

// ---- load helpers ----
__device__ __forceinline__ int   ldnt_i(const int* p)   { return __builtin_nontemporal_load(p); }
__device__ __forceinline__ float ldnt_f(const float* p) { return __builtin_nontemporal_load(p); }

// ---------------------------------------------------------------------------
// Build 1: per-bucket edge counts via LDS histograms.
__global__ __launch_bounds__(1024) void bucket_count(const int* __restrict__ rowA,
                                                     const int* __restrict__ rowH,
                                                     int* __restrict__ cntA,
                                                     int* __restrict__ cntH) {
    __shared__ int c[2 * NBK];
    for (int i = threadIdx.x; i < 2 * NBK; i += 1024) c[i] = 0;
    __syncthreads();
    int i = blockIdx.x * 1024 + threadIdx.x;
    const int stride = gridDim.x * 1024;
    for (; i < NNZ; i += stride) {
        atomicAdd(&c[ldnt_i(rowA + i) >> BSH], 1);
        atomicAdd(&c[NBK + (ldnt_i(rowH + i) >> BSH)], 1);
    }
    __syncthreads();
    for (int j = threadIdx.x; j < 2 * NBK; j += 1024) {
        const int v = c[j];
        if (v) atomicAdd(j < NBK ? (cntA + j) : (cntH + (j - NBK)), v);
    }
}

// Build 2: tiny serial scans -> bucket bases + scatter cursors.
__global__ __launch_bounds__(64) void bucket_scan(const int* __restrict__ cntA,
                                                  const int* __restrict__ cntH,
                                                  int* __restrict__ baseA, int* __restrict__ baseH,
                                                  int* __restrict__ gcurA, int* __restrict__ gcurH) {
    const int t = threadIdx.x;
    if (t == 0) {
        int run = 0;
        for (int j = 0; j < NBK; ++j) { baseA[j] = run; gcurA[j] = run; run += cntA[j]; }
        baseA[NBK] = run;
    } else if (t == 1) {
        int run = 0;
        for (int j = 0; j < NBK; ++j) { baseH[j] = run; gcurH[j] = run; run += cntH[j]; }
        baseH[NBK] = run;
    }
}

// Build 3: write-combining bucket scatter (stages (rl10<<18|col, val) by bucket).
__global__ __launch_bounds__(1024) void wc_scatter(const int* __restrict__ rowA, const int* __restrict__ colA,
                                                   const float* __restrict__ valA,
                                                   const int* __restrict__ rowH, const int* __restrict__ colH,
                                                   const float* __restrict__ valH,
                                                   int* __restrict__ gcurA, int* __restrict__ gcurH,
                                                   int2* __restrict__ stA, int2* __restrict__ stH) {
    __shared__ int  lcnt[2 * NBK];
    __shared__ int2 lent[2 * NBK * SLOT];
    for (int i = threadIdx.x; i < 2 * NBK; i += 1024) lcnt[i] = 0;
    __syncthreads();
    const int stride = gridDim.x * 1024;
    const int rounds = (NNZ + stride - 1) / stride;
    for (int rd = 0; rd < rounds; ++rd) {
        const int i = rd * stride + blockIdx.x * 1024 + threadIdx.x;
        if (i < NNZ) {
            {
                const int r = ldnt_i(rowA + i), cc = ldnt_i(colA + i);
                const float v = ldnt_f(valA + i);
                const int b = r >> BSH;
                const int2 pk = make_int2(((r & (BROWS - 1)) << 18) | cc, __float_as_int(v));
                const int n = atomicAdd(&lcnt[b], 1);
                if (n < SLOT) lent[b * SLOT + n] = pk;
                else          stA[atomicAdd(&gcurA[b], 1)] = pk;
            }
            {
                const int r = ldnt_i(rowH + i), cc = ldnt_i(colH + i);
                const float v = ldnt_f(valH + i);
                const int b = r >> BSH;
                const int gb = NBK + b;
                const int2 pk = make_int2(((r & (BROWS - 1)) << 18) | cc, __float_as_int(v));
                const int n = atomicAdd(&lcnt[gb], 1);
                if (n < SLOT) lent[gb * SLOT + n] = pk;
                else          stH[atomicAdd(&gcurH[b], 1)] = pk;
            }
        }
        __syncthreads();
        const int thresh = (rd == rounds - 1) ? 1 : 8;
        for (int gb = threadIdx.x; gb < 2 * NBK; gb += 1024) {
            int n = lcnt[gb]; if (n > SLOT) n = SLOT;
            if (n >= thresh) {
                int*  gc = (gb < NBK) ? &gcurA[gb] : &gcurH[gb - NBK];
                int2* st = (gb < NBK) ? stA : stH;
                const int p = atomicAdd(gc, n);
                for (int j = 0; j < n; ++j) st[p + j] = lent[gb * SLOT + j];
                lcnt[gb] = 0;
            }
        }
        __syncthreads();
    }
}

// Build 4: per-bucket (grp, seg)-sorted edge list + u8 seg offsets + grp bases.
__global__ __launch_bounds__(1024) void bucket_csr_seg(
    const int2* __restrict__ stA, const int2* __restrict__ stH,
    const int* __restrict__ baseA, const int* __restrict__ baseH,
    int* __restrict__ gbaseA, int* __restrict__ gbaseH,
    unsigned char* __restrict__ relA, unsigned char* __restrict__ relH,
    int2* __restrict__ edA, int2* __restrict__ edH) {
    const int isH = blockIdx.x >= NBK;
    const int b   = isH ? blockIdx.x - NBK : blockIdx.x;
    const int2* st   = isH ? stH   : stA;
    const int*  base = isH ? baseH : baseA;
    int*  gbase = isH ? gbaseH : gbaseA;
    unsigned char* rel = isH ? relH : relA;
    int2* ed = isH ? edH : edA;
    const int s = base[b], e = base[b + 1];
    const int t = threadIdx.x, lane = t & 63, wv = t >> 6;
    __shared__ int cnt[NKEY + 1];
    __shared__ int wsum[16], woff[16];
    __shared__ int carry, chtot;
    for (int i = t; i <= NKEY; i += 1024) cnt[i] = 0;
    if (t == 0) carry = 0;
    __syncthreads();
    for (int i = s + t; i < e; i += 1024) {
        const int pk = st[i].x;
        const int key = (pk >> 20) * NSEG + ((pk & 0x3FFFF) >> SEGSH);  // (rl10>>2)*37+seg
        atomicAdd(&cnt[key], 1);
    }
    __syncthreads();
    // exclusive scan of cnt[0..NKEY)
    for (int b2 = 0; b2 < NKEY; b2 += 1024) {
        const int idx = b2 + t;
        const int v = (idx < NKEY) ? cnt[idx] : 0;
        int x = v;
        #pragma unroll
        for (int off = 1; off < 64; off <<= 1) {
            const int n = __shfl_up(x, off);
            if (lane >= off) x += n;
        }
        if (lane == 63) wsum[wv] = x;
        __syncthreads();
        if (t == 0) { int a = 0; for (int w = 0; w < 16; ++w) { woff[w] = a; a += wsum[w]; } chtot = a; }
        __syncthreads();
        if (idx < NKEY) cnt[idx] = carry + woff[wv] + (x - v);
        __syncthreads();
        if (t == 0) carry += chtot;
        __syncthreads();
    }
    if (t == 0) cnt[NKEY] = e - s;
    __syncthreads();
    // metadata: grp base + u8 per-seg relative offsets
    if (t < GPB) {
        const int g = b * GPB + t;
        if (g < NGRP) {
            const int g0 = cnt[t * NSEG];
            gbase[g] = s + g0;
            const size_t rb = (size_t)g * 38;
            for (int sg = 0; sg < NSEG; ++sg)
                rel[rb + sg] = (unsigned char)(cnt[t * NSEG + sg] - g0);
            rel[rb + NSEG] = (unsigned char)(cnt[(t + 1) * NSEG] - g0);
        }
    }
    __syncthreads();
    // scatter into (grp, seg) order; record keeps rowlocal-in-grp (2 bits)
    for (int i = s + t; i < e; i += 1024) {
        const int2 pk = st[i];
        const int key = (pk.x >> 20) * NSEG + ((pk.x & 0x3FFFF) >> SEGSH);
        const int p = s + atomicAdd(&cnt[key], 1);
        ed[p] = make_int2((((pk.x >> 18) & 3) << 18) | (pk.x & 0x3FFFF), pk.y);
    }
}

// generic int copy (metadata relocation before the FINAL layer)
__global__ __launch_bounds__(256) void copy_int(const int* __restrict__ src,
                                                int* __restrict__ dst, int n) {
    const int i = blockIdx.x * blockDim.x + threadIdx.x;
    if (i < n) dst[i] = src[i];
}

// ---------------------------------------------------------------------------
template<bool FIRST>
__device__ __forceinline__ float2 ldrow(int c, const float* __restrict__ ue,
                                        const float* __restrict__ ie,
                                        const float* __restrict__ A, int lane) {
    const float* base;
    if constexpr (FIRST)
        base = (c < N_USERS) ? (ue + (size_t)c * E) : (ie + (size_t)(c - N_USERS) * E);
    else
        base = A + (size_t)c * E;
    return ((const float2*)base)[lane];
}

#define FMA4(rl, v, xv, a0, a1, a2, a3)                                      \
    do {                                                                      \
        if      (rl == 0) { a0.x = fmaf(v, xv.x, a0.x); a0.y = fmaf(v, xv.y, a0.y); } \
        else if (rl == 1) { a1.x = fmaf(v, xv.x, a1.x); a1.y = fmaf(v, xv.y, a1.y); } \
        else if (rl == 2) { a2.x = fmaf(v, xv.x, a2.x); a2.y = fmaf(v, xv.y, a2.y); } \
        else              { a3.x = fmaf(v, xv.x, a3.x); a3.y = fmaf(v, xv.y, a3.y); } \
    } while (0)

// Seg-tiled fused layer: wave owns 4 rows (one grp); sweep segs 0..36 so all
// co-resident blocks gather from the same ~2MB source window (L2-resident).
template<bool FIRST>
__global__ __launch_bounds__(256, 8) void fused_seg(
    const float* __restrict__ A,
    const float* __restrict__ ue, const float* __restrict__ ie,
    const int* __restrict__ gbaseA, const unsigned char* __restrict__ relA,
    const int2* __restrict__ edA,
    const int* __restrict__ gbaseH, const unsigned char* __restrict__ relH,
    const int2* __restrict__ edH,
    const float* __restrict__ Wk, const float* __restrict__ bk,
    int row0, float* __restrict__ out) {
    __shared__ float sP[TILE][E];
    __shared__ float sD[TILE][E];
    const int t = threadIdx.x, lane = t & 63, wv = t >> 6;
    const int g = (row0 >> 2) + blockIdx.x * 4 + wv;
    const int gbA = gbaseA[g], gbH = gbaseH[g];
    const size_t rb = (size_t)g * 38;
    float2 p0{0,0}, p1{0,0}, p2{0,0}, p3{0,0};
    float2 d0{0,0}, d1{0,0}, d2{0,0}, d3{0,0};

    for (int seg = 0; seg < NSEG; ++seg) {
        {   // low-pass adjacency
            int i = gbA + relA[rb + seg];
            const int e = gbA + relA[rb + seg + 1];
            for (; i + 1 < e; i += 2) {
                const int2 e0 = edA[i], e1 = edA[i + 1];
                const float2 x0 = ldrow<FIRST>(e0.x & 0x3FFFF, ue, ie, A, lane);
                const float2 x1 = ldrow<FIRST>(e1.x & 0x3FFFF, ue, ie, A, lane);
                const float v0 = __int_as_float(e0.y), v1 = __int_as_float(e1.y);
                const int r0_ = e0.x >> 18, r1_ = e1.x >> 18;
                FMA4(r0_, v0, x0, p0, p1, p2, p3);
                FMA4(r1_, v1, x1, p0, p1, p2, p3);
            }
            if (i < e) {
                const int2 e0 = edA[i];
                const float2 x0 = ldrow<FIRST>(e0.x & 0x3FFFF, ue, ie, A, lane);
                const float v0 = __int_as_float(e0.y);
                const int r0_ = e0.x >> 18;
                FMA4(r0_, v0, x0, p0, p1, p2, p3);
            }
        }
        {   // high-pass adjacency (same seg window -> shared L2 residency)
            int i = gbH + relH[rb + seg];
            const int e = gbH + relH[rb + seg + 1];
            for (; i + 1 < e; i += 2) {
                const int2 e0 = edH[i], e1 = edH[i + 1];
                const float2 x0 = ldrow<FIRST>(e0.x & 0x3FFFF, ue, ie, A, lane);
                const float2 x1 = ldrow<FIRST>(e1.x & 0x3FFFF, ue, ie, A, lane);
                const float v0 = __int_as_float(e0.y), v1 = __int_as_float(e1.y);
                const int r0_ = e0.x >> 18, r1_ = e1.x >> 18;
                FMA4(r0_, v0, x0, d0, d1, d2, d3);
                FMA4(r1_, v1, x1, d0, d1, d2, d3);
            }
            if (i < e) {
                const int2 e0 = edH[i];
                const float2 x0 = ldrow<FIRST>(e0.x & 0x3FFFF, ue, ie, A, lane);
                const float v0 = __int_as_float(e0.y);
                const int r0_ = e0.x >> 18;
                FMA4(r0_, v0, x0, d0, d1, d2, d3);
            }
        }
    }
    ((float2*)&sP[wv * 4 + 0][0])[lane] = p0;
    ((float2*)&sP[wv * 4 + 1][0])[lane] = p1;
    ((float2*)&sP[wv * 4 + 2][0])[lane] = p2;
    ((float2*)&sP[wv * 4 + 3][0])[lane] = p3;
    ((float2*)&sD[wv * 4 + 0][0])[lane] = d0;
    ((float2*)&sD[wv * 4 + 1][0])[lane] = d1;
    ((float2*)&sD[wv * 4 + 2][0])[lane] = d2;
    ((float2*)&sD[wv * 4 + 3][0])[lane] = d3;
    __syncthreads();

    // ---- phase 2: [TILE,256] @ [256,128] + bias ----
    const int j = t & (E - 1);
    const int h = t >> 7;
    float acc[8];
    const float bj = bk[j];
    #pragma unroll
    for (int rr = 0; rr < 8; ++rr) acc[rr] = bj;
    #pragma unroll 4
    for (int i = 0; i < E; ++i) {
        const float w = Wk[(size_t)i * E + j];
        #pragma unroll
        for (int rr = 0; rr < 8; ++rr) acc[rr] = fmaf(sP[h * 8 + rr][i], w, acc[rr]);
    }
    #pragma unroll 4
    for (int i = 0; i < E; ++i) {
        const float w = Wk[(size_t)(E + i) * E + j];
        #pragma unroll
        for (int rr = 0; rr < 8; ++rr) acc[rr] = fmaf(sD[h * 8 + rr][i], w, acc[rr]);
    }
    #pragma unroll
    for (int rr = 0; rr < 8; ++rr)
        out[(size_t)(row0 + blockIdx.x * TILE + h * 8 + rr) * E + j] = acc[rr];
}

// FINAL layer: only the 8192 requested rows; scans whole grp lists.
__global__ __launch_bounds__(256) void fused_final(
    const float* __restrict__ A,
    const int* __restrict__ gbaseA, const unsigned char* __restrict__ relA,
    const int2* __restrict__ edA,
    const int* __restrict__ gbaseH, const unsigned char* __restrict__ relH,
    const int2* __restrict__ edH,
    const float* __restrict__ Wk, const float* __restrict__ bk,
    const int* __restrict__ users, const int* __restrict__ items,
    float* __restrict__ out) {
    __shared__ float sP[TILE][E];
    __shared__ float sD[TILE][E];
    const int t = threadIdx.x, lane = t & 63, wv = t >> 6;

    #pragma unroll
    for (int q = 0; q < 4; ++q) {
        const int slot = blockIdx.x * TILE + wv * 4 + q;
        const int r = (slot < BATCH) ? users[slot] : (N_USERS + items[slot - BATCH]);
        const int g = r >> 2, rl = r & 3;
        float2 ap{0,0};
        {
            int i = gbaseA[g];
            const int e = i + relA[(size_t)g * 38 + NSEG];
            for (; i < e; ++i) {
                const int2 ee = edA[i];
                if ((ee.x >> 18) == rl) {
                    const float2 xv = ((const float2*)(A + (size_t)(ee.x & 0x3FFFF) * E))[lane];
                    const float v = __int_as_float(ee.y);
                    ap.x = fmaf(v, xv.x, ap.x); ap.y = fmaf(v, xv.y, ap.y);
                }
            }
        }
        ((float2*)&sP[wv * 4 + q][0])[lane] = ap;
        float2 ad{0,0};
        {
            int i = gbaseH[g];
            const int e = i + relH[(size_t)g * 38 + NSEG];
            for (; i < e; ++i) {
                const int2 ee = edH[i];
                if ((ee.x >> 18) == rl) {
                    const float2 xv = ((const float2*)(A + (size_t)(ee.x & 0x3FFFF) * E))[lane];
                    const float v = __int_as_float(ee.y);
                    ad.x = fmaf(v, xv.x, ad.x); ad.y = fmaf(v, xv.y, ad.y);
                }
            }
        }
        ((float2*)&sD[wv * 4 + q][0])[lane] = ad;
    }
    __syncthreads();

    const int j = t & (E - 1);
    const int h = t >> 7;
    float acc[8];
    const float bj = bk[j];
    #pragma unroll
    for (int rr = 0; rr < 8; ++rr) acc[rr] = bj;
    #pragma unroll 4
    for (int i = 0; i < E; ++i) {
        const float w = Wk[(size_t)i * E + j];
        #pragma unroll
        for (int rr = 0; rr < 8; ++rr) acc[rr] = fmaf(sP[h * 8 + rr][i], w, acc[rr]);
    }
    #pragma unroll 4
    for (int i = 0; i < E; ++i) {
        const float w = Wk[(size_t)(E + i) * E + j];
        #pragma unroll
        for (int rr = 0; rr < 8; ++rr) acc[rr] = fmaf(sD[h * 8 + rr][i], w, acc[rr]);
    }
    #pragma unroll
    for (int rr = 0; rr < 8; ++rr)
        out[(size_t)(blockIdx.x * TILE + h * 8 + rr) * E + j] = acc[rr];
}

// ---------------------------------------------------------------------------
extern "C" void kernel_launch(void* const* d_in, const int* in_sizes, int n_in,
                              void* d_out, int out_size, void* d_ws, size_t ws_size,
                              hipStream_t stream) {
    const float* user_emb = (const float*)d_in[0];
    const float* item_emb = (const float*)d_in[1];
    const float* adj_val  = (const float*)d_in[2];
    const float* hp_val   = (const float*)d_in[3];
    const float* W        = (const float*)d_in[4];
    const float* bias     = (const float*)d_in[5];
    const int*   adj_row  = (const int*)d_in[6];
    const int*   adj_col  = (const int*)d_in[7];
    const int*   hp_row   = (const int*)d_in[8];
    const int*   hp_col   = (const int*)d_in[9];
    const int*   users    = (const int*)d_in[10];
    const int*   items    = (const int*)d_in[11];
    float* out = (float*)d_out;

    // ---- workspace: exactly 230,400,000 B (proven available) ----
    float* buf0 = (float*)d_ws;                       // ego ping / build staging
    float* buf1 = buf0 + (size_t)NTOT * E;            // ego pong / FINAL metadata
    int2*  edA  = (int2*)(buf1 + (size_t)NTOT * E);   // seg-sorted edges A  38.4 MB
    int2*  edH  = edA + NNZ;                          // seg-sorted edges H  38.4 MB
    int2*  stA  = (int2*)buf0;                        // staging aliases buf0
    int2*  stH  = stA + NNZ;

    // ---- metadata in d_out (4.19 MB; fully overwritten by FINAL) ----
    int* gbA_d = (int*)d_out;                                  // 37500
    int* gbH_d = gbA_d + NGRP;                                 // 37500
    unsigned char* relA_d = (unsigned char*)(gbH_d + NGRP);    // 37500*38 B
    unsigned char* relH_d = relA_d + (size_t)NGRP * 38;
    int* cntA  = (int*)(relH_d + (size_t)NGRP * 38);
    int* cntH  = cntA + NBK;
    int* baseA = cntH + NBK;
    int* baseH = baseA + (NBK + 1);
    int* gcurA = baseH + (NBK + 1);
    int* gcurH = gcurA + NBK;
    const int META_INTS = (2 * NGRP * 4 + 2 * NGRP * 38) / 4;  // 787500

    // FINAL-time metadata copies live in buf1 (dead during FINAL)
    int* gbA_f = (int*)buf1;
    int* gbH_f = gbA_f + NGRP;
    unsigned char* relA_f = (unsigned char*)(gbH_f + NGRP);
    unsigned char* relH_f = relA_f + (size_t)NGRP * 38;

    // ---- build (grp,seg)-sorted edge lists (once; reused across layers) ----
    hipMemsetAsync(cntA, 0, (size_t)2 * NBK * sizeof(int), stream);
    bucket_count<<<256, 1024, 0, stream>>>(adj_row, hp_row, cntA, cntH);
    bucket_scan<<<1, 64, 0, stream>>>(cntA, cntH, baseA, baseH, gcurA, gcurH);
    wc_scatter<<<256, 1024, 0, stream>>>(adj_row, adj_col, adj_val,
                                         hp_row, hp_col, hp_val,
                                         gcurA, gcurH, stA, stH);
    bucket_csr_seg<<<2 * NBK, 1024, 0, stream>>>(stA, stH, baseA, baseH,
                                                 gbA_d, gbH_d, relA_d, relH_d, edA, edH);

    // ---- layers 0 and 1: 5 resident cohorts each (soft seg lockstep) ----
    for (int s5 = 0; s5 < 5; ++s5)
        fused_seg<true><<<SUBL, 256, 0, stream>>>(
            nullptr, user_emb, item_emb, gbA_d, relA_d, edA, gbH_d, relH_d, edH,
            W, bias, s5 * SUBL * TILE, buf1);
    for (int s5 = 0; s5 < 5; ++s5)
        fused_seg<false><<<SUBL, 256, 0, stream>>>(
            buf1, nullptr, nullptr, gbA_d, relA_d, edA, gbH_d, relH_d, edH,
            W + (size_t)2 * E * E, bias + E, s5 * SUBL * TILE, buf0);

    // relocate metadata out of d_out, then FINAL overwrites d_out
    copy_int<<<(META_INTS + 255) / 256, 256, 0, stream>>>(gbA_d, gbA_f, META_INTS);
    fused_final<<<(2 * BATCH) / TILE, 256, 0, stream>>>(
        buf0, gbA_f, relA_f, edA, gbH_f, relH_f, edH,
        W + (size_t)4 * E * E, bias + 2 * E, users, items, out);
}